// Round 5
// baseline (253.026 us; speedup 1.0000x reference)
//
#include <hip/hip_runtime.h>

typedef unsigned short u16;
typedef unsigned int u32;
typedef unsigned char u8;
typedef unsigned long long u64;

#define GG   512
#define NPG  90
#define NTOT (GG*NPG)
#define NED  921600
#define FIN  90
#define HC   64
#define KP   70
#define CAP  64
#define SA   68          // f32 LDS row stride; (68s+l)&31 puts 64 lanes on 32 banks 2-way (free)

// wf (f32 weights in ws) layout, float offsets:
#define WF_W1L 0
#define WF_W1R 5760
#define WF_W2L 11520
#define WF_W2R 15616
#define WF_B1  19712
#define WF_B2  19776
#define WF_FOLD 19840
#define WF_ZC  24320
#define WF_FLAG 24321

__device__ __forceinline__ float bf2f(u16 u) {
    union { u32 i; float f; } v; v.i = ((u32)u) << 16; return v.f;
}
__device__ __forceinline__ float bflo(u32 u) {
    union { u32 i; float f; } v; v.i = u << 16; return v.f;
}
__device__ __forceinline__ float bfhi(u32 u) {
    union { u32 i; float f; } v; v.i = u & 0xFFFF0000u; return v.f;
}
__device__ __forceinline__ u16 f2bf(float f) {
    union { float f; u32 i; } v; v.f = f;
    u32 r = (v.i + 0x7FFFu + ((v.i >> 16) & 1u)) >> 16;
    return (u16)r;
}
__device__ __forceinline__ float ldadp(const void* p, long long i, int isf32) {
    return isf32 ? ((const float*)p)[i] : bf2f(((const u16*)p)[i]);
}

// ---- merged prep: edge CSR build + weight convert + MLP fold, one dispatch.
// blocks 0..899: edges (1024 each). 900..977: weight convert. 978..995: fold.
__global__ __launch_bounds__(256) void k_pre(
    const u32* __restrict__ xw, const int* __restrict__ ei,
    const void* W1l, const void* W1r, const void* b1,
    const void* W2l, const void* W2r, const void* b2,
    const void* Wl1, const void* bl1, const void* Wl2, const void* bl2,
    int* __restrict__ cnt, u8* __restrict__ csr, float* __restrict__ wf)
{
    __shared__ int sf;
    const int t = threadIdx.x;
    const int b = blockIdx.x;

    if (b < 900) {
        // edge-int-width detect (wave-uniform, cheap)
        int lane = t & 63;
        u32 v = (lane < 16) ? (u32)ei[lane] : 0u;
        u64 bb = __ballot((lane & 1) && (v != 0));
        bool wide = (bb == 0ull);          // int64: odd (hi) words all zero
        int e0 = b * 1024 + t * 4;
        int s[4], d[4];
        if (wide) {
            uint4 s01 = *(const uint4*)(ei + 2 * e0);
            uint4 s23 = *(const uint4*)(ei + 2 * e0 + 4);
            uint4 d01 = *(const uint4*)(ei + 2 * (NED + e0));
            uint4 d23 = *(const uint4*)(ei + 2 * (NED + e0) + 4);
            s[0] = (int)s01.x; s[1] = (int)s01.z; s[2] = (int)s23.x; s[3] = (int)s23.z;
            d[0] = (int)d01.x; d[1] = (int)d01.z; d[2] = (int)d23.x; d[3] = (int)d23.z;
        } else {
            uint4 ss = *(const uint4*)(ei + e0);
            uint4 dd = *(const uint4*)(ei + NED + e0);
            s[0] = (int)ss.x; s[1] = (int)ss.y; s[2] = (int)ss.z; s[3] = (int)ss.w;
            d[0] = (int)dd.x; d[1] = (int)dd.y; d[2] = (int)dd.z; d[3] = (int)dd.w;
        }
        #pragma unroll
        for (int k = 0; k < 4; ++k) {
            int dk = d[k];
            if ((unsigned)dk >= NTOT) continue;
            int g = (unsigned)dk / NPG;
            int ls = s[k] - g * NPG;
            if ((unsigned)ls >= NPG) continue;
            int pos = atomicAdd(&cnt[dk], 1);
            if (pos < CAP) csr[dk * CAP + pos] = (u8)ls;
        }
        return;
    }

    // dtype detect for weight loads
    if (t < 64) {
        u32 e = (xw[t] >> 7) & 0xFF;       // exponent of low-half-as-bf16
        u64 bb = __ballot(e >= 136);       // impossible for N(0,1)-scale bf16
        if (t == 0) sf = (bb != 0ull) ? 1 : 0;
    }
    __syncthreads();
    const int f32 = sf;

    if (b < 978) {
        int i = (b - 900) * 256 + t;
        if      (i < 5760)  wf[i] = ldadp(W1l, i, f32);
        else if (i < 11520) wf[i] = ldadp(W1r, i - 5760, f32);
        else if (i < 15616) wf[i] = ldadp(W2l, i - 11520, f32);
        else if (i < 19712) wf[i] = ldadp(W2r, i - 15616, f32);
        else if (i < 19776) wf[i] = ldadp(b1, i - 19712, f32);
        else if (i < 19840) wf[i] = ldadp(b2, i - 19776, f32);
        if (b == 900 && t == 0) wf[WF_FLAG] = f32 ? 1.0f : 0.0f;
    } else {
        int m = (b - 978) * 256 + t;
        if (m < 4480) {
            float s = 0.f;
            for (int j = 0; j < HC; ++j)
                s += ldadp(Wl1, (long long)m * HC + j, f32) * ldadp(Wl2, j, f32);
            wf[WF_FOLD + m] = s;
        } else if (m == 4480) {
            float s = ldadp(bl2, 0, f32);
            for (int j = 0; j < HC; ++j)
                s += ldadp(bl1, j, f32) * ldadp(Wl2, j, f32);
            wf[WF_ZC] = s;
        }
    }
}

// ---- fused per-graph pipeline. 512 thr/block for 4 waves/SIMD latency hiding.
__global__ __launch_bounds__(512, 4) void k_fused(
    const void* __restrict__ x, const int* __restrict__ cnt,
    const u8* __restrict__ csr, const float* __restrict__ wf,
    void* __restrict__ dout)
{
    __shared__ __align__(16) char smem[55744];
    float* A1    = (float*)smem;                 // [90][68]: P -> r1 -> P2 -> h2
    float* A2    = (float*)(smem + 24480);       // [90][68]: xstage -> Q -> Q2
    u8*    s_adj = (u8*)(smem + 48960);          // [90][64]
    float* s_rc  = (float*)(smem + 54720);       // [90]
    float* s_key = (float*)(smem + 55080);       // [90]
    float* s_red = (float*)(smem + 55440);       // [8]
    u8*    s_deg = (u8*)(smem + 55472);          // [96]
    u16*   s_ord = (u16*)(smem + 55568);         // [72]

    const int g = blockIdx.x;
    const int t = threadIdx.x;
    const bool isf32 = (wf[WF_FLAG] > 0.5f);

    const u8* csr_g = csr + g * NPG * CAP;
    const u16*  xg16 = (const u16*)x + (size_t)g * NPG * FIN;
    const float* xg32 = (const float*)x + (size_t)g * NPG * FIN;

    // ---- stage: adjacency + degrees (+ x for bf16) ----
    if (t < 360) ((uint4*)s_adj)[t] = ((const uint4*)csr_g)[t];
    if (t < NPG) {
        int c = cnt[g * NPG + t];
        s_deg[t] = (u8)min(c, CAP);
        s_rc[t]  = 1.0f / (float)max(c, 1);
    }
    if (!isf32) {
        u32* sxw = (u32*)A2;                     // [90][46] u32 (x as bf16 pairs)
        const u32* src = (const u32*)xg16;
        for (int p = t; p < 4050; p += 512) {
            int row = p / 45, c = p - row * 45;
            sxw[row * 46 + c] = src[p];
        }
    }
    __syncthreads();  // B0

    const int trio = t & 31, q = t >> 5, jb = q * 4;   // 32 trios x 16 col-quads
    const int n0 = trio * 3;
    int rows[3];
    #pragma unroll
    for (int i = 0; i < 3; ++i) rows[i] = (n0 + i < NPG) ? n0 + i : 0;

    // ---- GEMM1: P = x@W1l, Q = x@W1r + b1 ----
    float accP[3][4], accQ[3][4];
    {
        float4 bq = *(const float4*)(wf + WF_B1 + jb);
        float bias[4] = {bq.x, bq.y, bq.z, bq.w};
        #pragma unroll
        for (int i = 0; i < 3; ++i)
            #pragma unroll
            for (int j = 0; j < 4; ++j) { accP[i][j] = 0.f; accQ[i][j] = bias[j]; }
    }
    {
        const u32* sxw = (const u32*)A2;
        for (int kk = 0; kk < 45; ++kk) {
            const int k0 = 2 * kk;
            float4 l0 = *(const float4*)(wf + WF_W1L + k0 * HC + jb);
            float4 l1 = *(const float4*)(wf + WF_W1L + (k0 + 1) * HC + jb);
            float4 r0 = *(const float4*)(wf + WF_W1R + k0 * HC + jb);
            float4 r1 = *(const float4*)(wf + WF_W1R + (k0 + 1) * HC + jb);
            float wl0[4] = {l0.x,l0.y,l0.z,l0.w};
            float wl1[4] = {l1.x,l1.y,l1.z,l1.w};
            float wr0[4] = {r0.x,r0.y,r0.z,r0.w};
            float wr1[4] = {r1.x,r1.y,r1.z,r1.w};
            float x0[3], x1[3];
            if (!isf32) {
                #pragma unroll
                for (int i = 0; i < 3; ++i) {
                    u32 xv = sxw[rows[i] * 46 + kk];
                    x0[i] = bflo(xv); x1[i] = bfhi(xv);
                }
            } else {
                #pragma unroll
                for (int i = 0; i < 3; ++i) {
                    x0[i] = xg32[rows[i] * FIN + k0];
                    x1[i] = xg32[rows[i] * FIN + k0 + 1];
                }
            }
            #pragma unroll
            for (int i = 0; i < 3; ++i)
                #pragma unroll
                for (int j = 0; j < 4; ++j) {
                    accP[i][j] += x0[i] * wl0[j] + x1[i] * wl1[j];
                    accQ[i][j] += x0[i] * wr0[j] + x1[i] * wr1[j];
                }
        }
    }
    __syncthreads();  // B1: x-stage reads done, A2 reusable
    #pragma unroll
    for (int i = 0; i < 3; ++i) {
        int n = n0 + i;
        if (n < NPG) {
            *(float4*)(A1 + n * SA + jb) =
                make_float4(accP[i][0], accP[i][1], accP[i][2], accP[i][3]);
            *(float4*)(A2 + n * SA + jb) =
                make_float4(accQ[i][0], accQ[i][1], accQ[i][2], accQ[i][3]);
        }
    }
    __syncthreads();  // B2

    // ---- Agg1 (column-per-lane, conflict-free): h1 = rc*sum(P[nbr]) + Q ----
    const int wv = t >> 6, ln = t & 63;
    float r1v[12];
    #pragma unroll
    for (int ii = 0; ii < 12; ++ii) {
        int n = wv + ii * 8;
        if (n < NPG) {
            int deg = s_deg[n];
            float rc = s_rc[n];
            const u8* arow = s_adj + n * CAP;
            float acc = 0.f;
            for (int e = 0; e < deg; ++e) {
                int s = arow[e];               // wave-uniform LDS broadcast
                acc += A1[s * SA + ln];        // 64 lanes -> 32 banks 2-way: free
            }
            float h = fmaf(rc, acc, A2[n * SA + ln]);
            size_t base = 512 + (size_t)(g * NPG + n) * HC + ln;
            if (isf32) ((float*)dout)[base] = h;
            else       ((u16*)dout)[base]   = f2bf(h);
            r1v[ii] = fmaxf(h, 0.f);
        }
    }
    __syncthreads();  // B3: all P/Q reads done
    #pragma unroll
    for (int ii = 0; ii < 12; ++ii) {
        int n = wv + ii * 8;
        if (n < NPG) A1[n * SA + ln] = r1v[ii];
    }
    __syncthreads();  // B4

    // ---- GEMM2: P2 = r1@W2l, Q2 = r1@W2r + b2 ----
    {
        float4 bq = *(const float4*)(wf + WF_B2 + jb);
        float bias[4] = {bq.x, bq.y, bq.z, bq.w};
        #pragma unroll
        for (int i = 0; i < 3; ++i)
            #pragma unroll
            for (int j = 0; j < 4; ++j) { accP[i][j] = 0.f; accQ[i][j] = bias[j]; }
    }
    {
        int rws[3];
        #pragma unroll
        for (int i = 0; i < 3; ++i) rws[i] = rows[i] * SA;
        for (int k = 0; k < HC; ++k) {
            float4 l = *(const float4*)(wf + WF_W2L + k * HC + jb);
            float4 r = *(const float4*)(wf + WF_W2R + k * HC + jb);
            float wlv[4] = {l.x,l.y,l.z,l.w};
            float wrv[4] = {r.x,r.y,r.z,r.w};
            #pragma unroll
            for (int i = 0; i < 3; ++i) {
                float rv = A1[rws[i] + k];
                #pragma unroll
                for (int j = 0; j < 4; ++j) {
                    accP[i][j] += rv * wlv[j];
                    accQ[i][j] += rv * wrv[j];
                }
            }
        }
    }
    __syncthreads();  // B5: all r1 reads done
    #pragma unroll
    for (int i = 0; i < 3; ++i) {
        int n = n0 + i;
        if (n < NPG) {
            *(float4*)(A1 + n * SA + jb) =
                make_float4(accP[i][0], accP[i][1], accP[i][2], accP[i][3]);
            *(float4*)(A2 + n * SA + jb) =
                make_float4(accQ[i][0], accQ[i][1], accQ[i][2], accQ[i][3]);
        }
    }
    __syncthreads();  // B6

    // ---- Agg2: h2 = rc*sum(P2[nbr]) + Q2 ; key = col 63 ----
    float h2v[12];
    #pragma unroll
    for (int ii = 0; ii < 12; ++ii) {
        int n = wv + ii * 8;
        if (n < NPG) {
            int deg = s_deg[n];
            float rc = s_rc[n];
            const u8* arow = s_adj + n * CAP;
            float acc = 0.f;
            for (int e = 0; e < deg; ++e) {
                int s = arow[e];
                acc += A1[s * SA + ln];
            }
            float h = fmaf(rc, acc, A2[n * SA + ln]);
            h2v[ii] = h;
            if (ln == 63) s_key[n] = h;
        }
    }
    __syncthreads();  // B7: all P2/Q2 reads done; s_key complete
    #pragma unroll
    for (int ii = 0; ii < 12; ++ii) {
        int n = wv + ii * 8;
        if (n < NPG) A1[n * SA + ln] = h2v[ii];
    }
    // stable descending rank (== stable argsort(-key))
    if (t < NPG) {
        float my = s_key[t];
        int r = 0;
        for (int m2 = 0; m2 < NPG; ++m2) {
            float km = s_key[m2];
            r += (km > my) || (km == my && m2 < t);
        }
        if (r < KP) s_ord[r] = (u16)t;
    }
    __syncthreads();  // B8

    // ---- folded MLP: z = sum p*W_fold + zc ; sigmoid ----
    float zp = 0.f;
    for (int p = t; p < KP * HC; p += 512) {
        int i = p >> 6, c = p & 63;
        int nn = s_ord[i];
        zp += A1[nn * SA + c] * wf[WF_FOLD + p];
    }
    #pragma unroll
    for (int off = 32; off > 0; off >>= 1) zp += __shfl_down(zp, off);
    if ((t & 63) == 0) s_red[t >> 6] = zp;
    __syncthreads();  // B9
    if (t == 0) {
        float z = wf[WF_ZC];
        #pragma unroll
        for (int w = 0; w < 8; ++w) z += s_red[w];
        float sg = 1.0f / (1.0f + expf(-z));
        if (isf32) ((float*)dout)[g] = sg;
        else       ((u16*)dout)[g]   = f2bf(sg);
    }
}

extern "C" void kernel_launch(void* const* d_in, const int* in_sizes, int n_in,
                              void* d_out, int out_size, void* d_ws, size_t ws_size,
                              hipStream_t stream) {
    const void* x   = d_in[0];
    const int*  ei  = (const int*)d_in[1];
    const void* W1l = d_in[3];
    const void* W1r = d_in[4];
    const void* b1  = d_in[5];
    const void* W2l = d_in[6];
    const void* W2r = d_in[7];
    const void* b2  = d_in[8];
    const void* Wl1 = d_in[9];
    const void* bl1 = d_in[10];
    const void* Wl2 = d_in[11];
    const void* bl2 = d_in[12];

    char* ws    = (char*)d_ws;
    int*   cnt  = (int*)(ws + 64);              // 184,320 B
    u8*    csr  = (u8*)(ws + 184384);           // 2,949,120 B
    float* wf   = (float*)(ws + 3133504);       // 97,288 B   (total ~3.23 MB)

    hipMemsetAsync(cnt, 0, NTOT * sizeof(int), stream);
    k_pre<<<996, 256, 0, stream>>>((const u32*)x, ei, W1l, W1r, b1, W2l, W2r, b2,
                                   Wl1, bl1, Wl2, bl2, cnt, csr, wf);
    k_fused<<<GG, 512, 0, stream>>>(x, cnt, csr, wf, d_out);
}

// Round 6
// 222.878 us; speedup vs baseline: 1.1353x; 1.1353x over previous
//
#include <hip/hip_runtime.h>

typedef unsigned short u16;
typedef unsigned int u32;
typedef unsigned char u8;
typedef unsigned long long u64;

#define GG   512
#define NPG  90
#define NTOT (GG*NPG)
#define NED  921600
#define FIN  90
#define HC   64
#define KP   70

#define SAD  90   // A LDS stride (packed; 2-way max: trio t vs t+16 — free)
#define SP   68   // P LDS stride (float4 rows; 2-way on b128 — free)
#define SR   67   // r1/h2 LDS stride (scalar; 201=9*trio mod 32 bijective — conflict-free)
#define SXW  46   // bf16-x u32 stride (2-way — free)

// wf (f32 weights in ws) layout, float offsets:
#define WF_W1L 0
#define WF_W1R 5760
#define WF_W2L 11520
#define WF_W2R 15616
#define WF_B1  19712
#define WF_B2  19776
#define WF_FOLD 19840
#define WF_ZC  24320
#define WF_FLAG 24321

__device__ __forceinline__ float bf2f(u16 u) {
    union { u32 i; float f; } v; v.i = ((u32)u) << 16; return v.f;
}
__device__ __forceinline__ float bflo(u32 u) {
    union { u32 i; float f; } v; v.i = u << 16; return v.f;
}
__device__ __forceinline__ float bfhi(u32 u) {
    union { u32 i; float f; } v; v.i = u & 0xFFFF0000u; return v.f;
}
__device__ __forceinline__ u16 f2bf(float f) {
    union { float f; u32 i; } v; v.f = f;
    u32 r = (v.i + 0x7FFFu + ((v.i >> 16) & 1u)) >> 16;
    return (u16)r;
}
__device__ __forceinline__ float ldadp(const void* p, long long i, int isf32) {
    return isf32 ? ((const float*)p)[i] : bf2f(((const u16*)p)[i]);
}

// ---- merged prep: dense-A build (atomic +1.0f) + weight convert + MLP fold.
// blocks 0..899: edges (1024 each). 900..977: weight convert. 978..995: fold.
__global__ __launch_bounds__(256) void k_pre(
    const u32* __restrict__ xw, const int* __restrict__ ei,
    const void* W1l, const void* W1r, const void* b1,
    const void* W2l, const void* W2r, const void* b2,
    const void* Wl1, const void* bl1, const void* Wl2, const void* bl2,
    float* __restrict__ A, float* __restrict__ wf)
{
    __shared__ int sf;
    const int t = threadIdx.x;
    const int b = blockIdx.x;

    if (b < 900) {
        int lane = t & 63;
        u32 v = (lane < 16) ? (u32)ei[lane] : 0u;
        u64 bb = __ballot((lane & 1) && (v != 0));
        bool wide = (bb == 0ull);          // int64: odd (hi) words all zero
        int e0 = b * 1024 + t * 4;
        int s[4], d[4];
        if (wide) {
            uint4 s01 = *(const uint4*)(ei + 2 * e0);
            uint4 s23 = *(const uint4*)(ei + 2 * e0 + 4);
            uint4 d01 = *(const uint4*)(ei + 2 * (NED + e0));
            uint4 d23 = *(const uint4*)(ei + 2 * (NED + e0) + 4);
            s[0] = (int)s01.x; s[1] = (int)s01.z; s[2] = (int)s23.x; s[3] = (int)s23.z;
            d[0] = (int)d01.x; d[1] = (int)d01.z; d[2] = (int)d23.x; d[3] = (int)d23.z;
        } else {
            uint4 ss = *(const uint4*)(ei + e0);
            uint4 dd = *(const uint4*)(ei + NED + e0);
            s[0] = (int)ss.x; s[1] = (int)ss.y; s[2] = (int)ss.z; s[3] = (int)ss.w;
            d[0] = (int)dd.x; d[1] = (int)dd.y; d[2] = (int)dd.z; d[3] = (int)dd.w;
        }
        #pragma unroll
        for (int k = 0; k < 4; ++k) {
            int dk = d[k];
            if ((unsigned)dk >= NTOT) continue;
            int g = (unsigned)dk / NPG;
            int dl = dk - g * NPG;
            int ls = s[k] - g * NPG;
            if ((unsigned)ls >= NPG) continue;
            atomicAdd(&A[(size_t)g * 8100 + dl * NPG + ls], 1.0f);
        }
        return;
    }

    if (t < 64) {
        u32 e = (xw[t] >> 7) & 0xFF;       // exponent of low-half-as-bf16
        u64 bb = __ballot(e >= 136);       // impossible for N(0,1)-scale bf16
        if (t == 0) sf = (bb != 0ull) ? 1 : 0;
    }
    __syncthreads();
    const int f32 = sf;

    if (b < 978) {
        int i = (b - 900) * 256 + t;
        if      (i < 5760)  wf[i] = ldadp(W1l, i, f32);
        else if (i < 11520) wf[i] = ldadp(W1r, i - 5760, f32);
        else if (i < 15616) wf[i] = ldadp(W2l, i - 11520, f32);
        else if (i < 19712) wf[i] = ldadp(W2r, i - 15616, f32);
        else if (i < 19776) wf[i] = ldadp(b1, i - 19712, f32);
        else if (i < 19840) wf[i] = ldadp(b2, i - 19776, f32);
        if (b == 900 && t == 0) wf[WF_FLAG] = f32 ? 1.0f : 0.0f;
    } else {
        int m = (b - 978) * 256 + t;
        if (m < 4480) {
            float s = 0.f;
            for (int j = 0; j < HC; ++j)
                s += ldadp(Wl1, (long long)m * HC + j, f32) * ldadp(Wl2, j, f32);
            wf[WF_FOLD + m] = s;
        } else if (m == 4480) {
            float s = ldadp(bl2, 0, f32);
            for (int j = 0; j < HC; ++j)
                s += ldadp(bl1, j, f32) * ldadp(Wl2, j, f32);
            wf[WF_ZC] = s;
        }
    }
}

// ---- fused per-graph pipeline: every phase a register-tiled GEMM (3x8/thread)
__global__ __launch_bounds__(256, 2) void k_fused(
    const void* __restrict__ x, const float* __restrict__ A,
    const float* __restrict__ wf, void* __restrict__ dout)
{
    __shared__ __align__(16) char smem[57840];
    float* R1   = (float*)smem;                  // 6120 f: x(bf16)/P/r1/P2/h2
    float* As   = (float*)(smem + 24480);        // [90][90] packed A
    float* s_rc = (float*)(smem + 56880);        // [90]
    float* s_key= (float*)(smem + 57264);        // [90]
    float* s_red= (float*)(smem + 57648);        // [4]
    u16*  s_ord = (u16*)(smem + 57680);          // [72]

    const int g = blockIdx.x;
    const int t = threadIdx.x;
    const bool isf32 = (wf[WF_FLAG] > 0.5f);
    const float* Ag = A + (size_t)g * 8100;
    const float* xg32 = (const float*)x + (size_t)g * 8100;

    // ---- stage A (identity copy) + x (bf16 path only) ----
    for (int p = t; p < 8100; p += 256) As[p] = Ag[p];
    if (!isf32) {
        const u32* src = (const u32*)((const u16*)x + (size_t)g * 8100);
        u32* sxw = (u32*)R1;
        for (int p = t; p < 4050; p += 256) {
            int row = p / 45, c = p - row * 45;
            sxw[row * SXW + c] = src[p];
        }
    }
    __syncthreads();  // B0
    // rc from A row-sums (cnt == in-degree incl. duplicates)
    if (t < NPG) {
        float s = 0.f;
        for (int k = 0; k < NPG; ++k) s += As[t * SAD + k];
        s_rc[t] = 1.0f / fmaxf(s, 1.0f);
    }

    const int trio = t & 31, jg = t >> 5, jb = jg * 8;
    const int n0 = trio * 3;
    int rows[3];
    #pragma unroll
    for (int i = 0; i < 3; ++i) rows[i] = (n0 + i < NPG) ? n0 + i : 0;

    // ---- GEMM1: P = x@W1l, Q = x@W1r + b1 (both in regs) ----
    float accP[3][8], accQ[3][8];
    {
        float4 q0 = *(const float4*)(wf + WF_B1 + jb);
        float4 q1 = *(const float4*)(wf + WF_B1 + jb + 4);
        float bias[8] = {q0.x,q0.y,q0.z,q0.w,q1.x,q1.y,q1.z,q1.w};
        #pragma unroll
        for (int i = 0; i < 3; ++i)
            #pragma unroll
            for (int j = 0; j < 8; ++j) { accP[i][j] = 0.f; accQ[i][j] = bias[j]; }
    }
    {
        const u32* sxw = (const u32*)R1;
        for (int kk = 0; kk < 45; ++kk) {
            const int k0 = 2 * kk;
            const float* wl = wf + WF_W1L + k0 * HC + jb;
            const float* wr = wf + WF_W1R + k0 * HC + jb;
            float4 l00 = *(const float4*)(wl);
            float4 l01 = *(const float4*)(wl + 4);
            float4 l10 = *(const float4*)(wl + HC);
            float4 l11 = *(const float4*)(wl + HC + 4);
            float4 r00 = *(const float4*)(wr);
            float4 r01 = *(const float4*)(wr + 4);
            float4 r10 = *(const float4*)(wr + HC);
            float4 r11 = *(const float4*)(wr + HC + 4);
            float wl0[8] = {l00.x,l00.y,l00.z,l00.w,l01.x,l01.y,l01.z,l01.w};
            float wl1[8] = {l10.x,l10.y,l10.z,l10.w,l11.x,l11.y,l11.z,l11.w};
            float wr0[8] = {r00.x,r00.y,r00.z,r00.w,r01.x,r01.y,r01.z,r01.w};
            float wr1[8] = {r10.x,r10.y,r10.z,r10.w,r11.x,r11.y,r11.z,r11.w};
            float x0[3], x1[3];
            if (!isf32) {
                #pragma unroll
                for (int i = 0; i < 3; ++i) {
                    u32 xv = sxw[rows[i] * SXW + kk];
                    x0[i] = bflo(xv); x1[i] = bfhi(xv);
                }
            } else {
                #pragma unroll
                for (int i = 0; i < 3; ++i) {
                    x0[i] = xg32[rows[i] * FIN + k0];
                    x1[i] = xg32[rows[i] * FIN + k0 + 1];
                }
            }
            #pragma unroll
            for (int i = 0; i < 3; ++i)
                #pragma unroll
                for (int j = 0; j < 8; ++j) {
                    accP[i][j] += x0[i] * wl0[j] + x1[i] * wl1[j];
                    accQ[i][j] += x0[i] * wr0[j] + x1[i] * wr1[j];
                }
        }
    }
    __syncthreads();  // B1: x reads done
    #pragma unroll
    for (int i = 0; i < 3; ++i) {
        int n = n0 + i;
        if (n < NPG) {
            *(float4*)(R1 + n * SP + jb) =
                make_float4(accP[i][0], accP[i][1], accP[i][2], accP[i][3]);
            *(float4*)(R1 + n * SP + jb + 4) =
                make_float4(accP[i][4], accP[i][5], accP[i][6], accP[i][7]);
        }
    }
    __syncthreads();  // B2

    // ---- Agg1 (dense GEMM): h1 = rc*(A@P) + Q ; x_train out; r1 regs ----
    float r1v[3][8];
    {
        float accA[3][8];
        #pragma unroll
        for (int i = 0; i < 3; ++i)
            #pragma unroll
            for (int j = 0; j < 8; ++j) accA[i][j] = 0.f;
        for (int k = 0; k < NPG; ++k) {
            float4 p0 = *(const float4*)(R1 + k * SP + jb);
            float4 p1 = *(const float4*)(R1 + k * SP + jb + 4);
            float pv[8] = {p0.x,p0.y,p0.z,p0.w,p1.x,p1.y,p1.z,p1.w};
            float av[3];
            #pragma unroll
            for (int i = 0; i < 3; ++i) av[i] = As[rows[i] * SAD + k];
            #pragma unroll
            for (int i = 0; i < 3; ++i)
                #pragma unroll
                for (int j = 0; j < 8; ++j) accA[i][j] += av[i] * pv[j];
        }
        #pragma unroll
        for (int i = 0; i < 3; ++i) {
            int n = n0 + i;
            if (n < NPG) {
                float rc = s_rc[n];
                float h[8];
                #pragma unroll
                for (int j = 0; j < 8; ++j) h[j] = fmaf(rc, accA[i][j], accQ[i][j]);
                size_t base = 512 + (size_t)(g * NPG + n) * HC + jb;
                if (isf32) {
                    *(float4*)((float*)dout + base) = make_float4(h[0],h[1],h[2],h[3]);
                    *(float4*)((float*)dout + base + 4) = make_float4(h[4],h[5],h[6],h[7]);
                } else {
                    uint4 pk;
                    pk.x = (u32)f2bf(h[0]) | ((u32)f2bf(h[1]) << 16);
                    pk.y = (u32)f2bf(h[2]) | ((u32)f2bf(h[3]) << 16);
                    pk.z = (u32)f2bf(h[4]) | ((u32)f2bf(h[5]) << 16);
                    pk.w = (u32)f2bf(h[6]) | ((u32)f2bf(h[7]) << 16);
                    *(uint4*)((u16*)dout + base) = pk;
                }
                #pragma unroll
                for (int j = 0; j < 8; ++j) r1v[i][j] = fmaxf(h[j], 0.f);
            }
        }
    }
    __syncthreads();  // B3: P reads done
    #pragma unroll
    for (int i = 0; i < 3; ++i) {
        int n = n0 + i;
        if (n < NPG)
            #pragma unroll
            for (int j = 0; j < 8; ++j) R1[n * SR + jb + j] = r1v[i][j];
    }
    __syncthreads();  // B4

    // ---- GEMM2: P2 = r1@W2l, Q2 = r1@W2r + b2 ----
    {
        float4 q0 = *(const float4*)(wf + WF_B2 + jb);
        float4 q1 = *(const float4*)(wf + WF_B2 + jb + 4);
        float bias[8] = {q0.x,q0.y,q0.z,q0.w,q1.x,q1.y,q1.z,q1.w};
        #pragma unroll
        for (int i = 0; i < 3; ++i)
            #pragma unroll
            for (int j = 0; j < 8; ++j) { accP[i][j] = 0.f; accQ[i][j] = bias[j]; }
    }
    for (int k = 0; k < HC; ++k) {
        const float* wl = wf + WF_W2L + k * HC + jb;
        const float* wr = wf + WF_W2R + k * HC + jb;
        float4 l0 = *(const float4*)(wl);
        float4 l1 = *(const float4*)(wl + 4);
        float4 r0 = *(const float4*)(wr);
        float4 r1q = *(const float4*)(wr + 4);
        float wlv[8] = {l0.x,l0.y,l0.z,l0.w,l1.x,l1.y,l1.z,l1.w};
        float wrv[8] = {r0.x,r0.y,r0.z,r0.w,r1q.x,r1q.y,r1q.z,r1q.w};
        float rv[3];
        #pragma unroll
        for (int i = 0; i < 3; ++i) rv[i] = R1[rows[i] * SR + k];
        #pragma unroll
        for (int i = 0; i < 3; ++i)
            #pragma unroll
            for (int j = 0; j < 8; ++j) {
                accP[i][j] += rv[i] * wlv[j];
                accQ[i][j] += rv[i] * wrv[j];
            }
    }
    __syncthreads();  // B5: r1 reads done
    #pragma unroll
    for (int i = 0; i < 3; ++i) {
        int n = n0 + i;
        if (n < NPG) {
            *(float4*)(R1 + n * SP + jb) =
                make_float4(accP[i][0], accP[i][1], accP[i][2], accP[i][3]);
            *(float4*)(R1 + n * SP + jb + 4) =
                make_float4(accP[i][4], accP[i][5], accP[i][6], accP[i][7]);
        }
    }
    __syncthreads();  // B6

    // ---- Agg2 (dense GEMM): h2 = rc*(A@P2) + Q2 ; key = col 63 ----
    float h2v[3][8];
    {
        float accA[3][8];
        #pragma unroll
        for (int i = 0; i < 3; ++i)
            #pragma unroll
            for (int j = 0; j < 8; ++j) accA[i][j] = 0.f;
        for (int k = 0; k < NPG; ++k) {
            float4 p0 = *(const float4*)(R1 + k * SP + jb);
            float4 p1 = *(const float4*)(R1 + k * SP + jb + 4);
            float pv[8] = {p0.x,p0.y,p0.z,p0.w,p1.x,p1.y,p1.z,p1.w};
            float av[3];
            #pragma unroll
            for (int i = 0; i < 3; ++i) av[i] = As[rows[i] * SAD + k];
            #pragma unroll
            for (int i = 0; i < 3; ++i)
                #pragma unroll
                for (int j = 0; j < 8; ++j) accA[i][j] += av[i] * pv[j];
        }
        #pragma unroll
        for (int i = 0; i < 3; ++i) {
            int n = n0 + i;
            if (n < NPG) {
                float rc = s_rc[n];
                #pragma unroll
                for (int j = 0; j < 8; ++j)
                    h2v[i][j] = fmaf(rc, accA[i][j], accQ[i][j]);
                if (jg == 7) s_key[n] = h2v[i][7];
            }
        }
    }
    __syncthreads();  // B7: P2 reads done; s_key complete
    #pragma unroll
    for (int i = 0; i < 3; ++i) {
        int n = n0 + i;
        if (n < NPG)
            #pragma unroll
            for (int j = 0; j < 8; ++j) R1[n * SR + jb + j] = h2v[i][j];
    }
    // stable descending rank (== stable argsort(-key))
    if (t < NPG) {
        float my = s_key[t];
        int r = 0;
        for (int m2 = 0; m2 < NPG; ++m2) {
            float km = s_key[m2];
            r += (km > my) || (km == my && m2 < t);
        }
        if (r < KP) s_ord[r] = (u16)t;
    }
    __syncthreads();  // B8

    // ---- folded MLP: z = sum p*W_fold + zc ; sigmoid ----
    float zp = 0.f;
    for (int p = t; p < KP * HC; p += 256) {
        int i = p >> 6, c = p & 63;
        int nn = s_ord[i];
        zp += R1[nn * SR + c] * wf[WF_FOLD + p];
    }
    #pragma unroll
    for (int off = 32; off > 0; off >>= 1) zp += __shfl_down(zp, off);
    if ((t & 63) == 0) s_red[t >> 6] = zp;
    __syncthreads();  // B9
    if (t == 0) {
        float z = s_red[0] + s_red[1] + s_red[2] + s_red[3] + wf[WF_ZC];
        float sg = 1.0f / (1.0f + expf(-z));
        if (isf32) ((float*)dout)[g] = sg;
        else       ((u16*)dout)[g]   = f2bf(sg);
    }
}

extern "C" void kernel_launch(void* const* d_in, const int* in_sizes, int n_in,
                              void* d_out, int out_size, void* d_ws, size_t ws_size,
                              hipStream_t stream) {
    const void* x   = d_in[0];
    const int*  ei  = (const int*)d_in[1];
    const void* W1l = d_in[3];
    const void* W1r = d_in[4];
    const void* b1  = d_in[5];
    const void* W2l = d_in[6];
    const void* W2r = d_in[7];
    const void* b2  = d_in[8];
    const void* Wl1 = d_in[9];
    const void* bl1 = d_in[10];
    const void* Wl2 = d_in[11];
    const void* bl2 = d_in[12];

    char* ws   = (char*)d_ws;
    float* A   = (float*)(ws + 64);             // 16,588,800 B (512 x 90 x 90 f32)
    float* wf  = (float*)(ws + 64 + 16588800);  // 97,288 B (total ~16.7 MB)

    hipMemsetAsync(A, 0, (size_t)GG * 8100 * sizeof(float), stream);
    k_pre<<<996, 256, 0, stream>>>((const u32*)x, ei, W1l, W1r, b1, W2l, W2r, b2,
                                   Wl1, bl1, Wl2, bl2, A, wf);
    k_fused<<<GG, 256, 0, stream>>>(x, A, wf, d_out);
}